// Round 11
// baseline (343.036 us; speedup 1.0000x reference)
//
#include <hip/hip_runtime.h>

// ---------------------------------------------------------------------------
// GAT 2-layer forward on MI355X. Round 24:
//  - Round-23 post-mortem: NEW BEST 339.0us (-22.9). No-max deferred-norm
//    softmax landed. Top-5 now = workspace re-poison fills (reset artifacts,
//    outside dur_us); all our kernels < 40.3us.
//  - This round: kill the two standalone dot passes by fusing them into the
//    GEMM epilogue that already holds their input tile in LDS:
//    * a1_dots -> encoder epilogue (ATT=1: 8-head dots vs v_s1/v_d1 slices)
//    * a2_dots -> conv2-proj epilogue (ATT=2: 1-head dots vs att_src2/dst2)
//    Partial dots per 128-col block, 4 threads/row over hsh, shfl-combine,
//    atomicAdd (2 blocks contend/addr). Zero-init merged into the existing
//    memset (contiguous allocs). -2 launches, -20MB HBM re-reads.
//  - Everything else = round 23.
// ---------------------------------------------------------------------------

#define NEG_SLOPE 0.2f

typedef __attribute__((ext_vector_type(8))) short bf16x8;
typedef __attribute__((ext_vector_type(4))) float f32x4;

__device__ __forceinline__ float bf2f(unsigned short u) {
  return __uint_as_float(((unsigned)u) << 16);
}
__device__ __forceinline__ unsigned short f2bf(float f) {
  unsigned u = __float_as_uint(f);
  u += 0x7fffu + ((u >> 16) & 1u);   // round-to-nearest-even
  return (unsigned short)(u >> 16);
}

__device__ __forceinline__ void async_copy16(const void* g, void* l) {
  __builtin_amdgcn_global_load_lds(
      (const __attribute__((address_space(1))) unsigned int*)g,
      (__attribute__((address_space(3))) unsigned int*)l, 16, 0, 0);
}

// ---------------------------------------------------------------------------
// prep: fold W_node/W_col halves, convert MFMA operands to bf16, and compute
// v_s1/v_d1 = att1 @ W1 (per-head 256-dots) as an extra index range.
__global__ void prep(const float* __restrict__ Wn, const float* __restrict__ Wc,
                     const float* __restrict__ W1, const float* __restrict__ W2,
                     const float* __restrict__ Wout,
                     const float* __restrict__ cons, const float* __restrict__ cols,
                     const float* __restrict__ att_s1, const float* __restrict__ att_d1,
                     unsigned short* __restrict__ Wn_b, unsigned short* __restrict__ Wc_b,
                     unsigned short* __restrict__ W1b, unsigned short* __restrict__ W2b,
                     unsigned short* __restrict__ Woutb,
                     unsigned short* __restrict__ consb, unsigned short* __restrict__ colsb,
                     float* __restrict__ v_s1, float* __restrict__ v_d1,
                     int n_cons, int n_cols) {
  const int S0 = 256 * 64;
  const int S1 = 256 * 128;
  const int S2 = 2048 * 256;
  const int S3 = 256 * 2048;
  const int S4 = 128 * 256;
  const int S5 = 2048;                 // v1 (h,k) items
  int total = S0 + S1 + S2 + S3 + S4 + n_cons + n_cols + S5;
  for (int idx = blockIdx.x * 256 + threadIdx.x; idx < total; idx += gridDim.x * 256) {
    int i = idx;
    if (i < S0) { int o = i >> 6, j = i & 63;
      Wn_b[i] = f2bf(Wn[o * 128 + j] + Wn[o * 128 + 64 + j]); continue; }
    i -= S0;
    if (i < S1) { int o = i >> 7, j = i & 127;
      Wc_b[i] = f2bf(Wc[o * 256 + j] + Wc[o * 256 + 128 + j]); continue; }
    i -= S1;
    if (i < S2) { W1b[i] = f2bf(W1[i]); continue; }
    i -= S2;
    if (i < S3) { W2b[i] = f2bf(W2[i]); continue; }
    i -= S3;
    if (i < S4) { Woutb[i] = f2bf(Wout[i]); continue; }
    i -= S4;
    if (i < n_cons) { consb[i] = f2bf(cons[i]); continue; }
    i -= n_cons;
    if (i < n_cols) { colsb[i] = f2bf(cols[i]); continue; }
    i -= n_cols;
    { // v1: i in [0,2048), h = i>>8, k = i&255
      int h = i >> 8, k = i & 255;
      const float* Wrow = W1 + (size_t)h * 256 * 256 + k;
      const float* as = att_s1 + h * 256;
      const float* ad = att_d1 + h * 256;
      float s = 0.f, d = 0.f;
      for (int c = 0; c < 256; ++c) {
        float w = Wrow[(size_t)c * 256];
        s += as[c] * w;
        d += ad[c] * w;
      }
      v_s1[i] = s; v_d1[i] = d;
    }
  }
}

// ---------------------------------------------------------------------------
// bf16 MFMA GEMM, B^T layout: C[m,n] = sum_k A[m, koff+k] * W[n,k] (+bias,relu).
// 512 threads, 8 waves; wave w owns rows [(w&3)*32,+32) x cols [(w>>2)*64,+64)
// of the 128x128 tile. XOR-swizzled staging, coalesced bf16 epilogue via LDS.
// SWZ: XCD-chunked bijective block swizzle (m204) — BDIAG conv1-proj only.
// ATT: fused attention partial dots from the hsh tile (C_BF16 only):
//   ATT=1: 8-head dots vs att_vs/att_vd slices (v[h*256+n0+c]), out [row*8+h]
//   ATT=2: 1-head dots vs att_vs/att_vd (v[n0+c]), out [row]
// Partials atomicAdd'ed (gx=2 blocks contend per address); outputs must be
// zero-initialized before launch.
template <bool C_BF16, bool BIAS, bool RELU, bool BDIAG, bool SWZ, int ATT>
__global__ __launch_bounds__(512) void gemm_mfma_bt(const unsigned short* __restrict__ A,
                                                    const unsigned short* __restrict__ W,
                                                    const float* __restrict__ bias,
                                                    void* __restrict__ Cv,
                                                    int M, int K, int Nout, int lda,
                                                    const float* __restrict__ att_vs,
                                                    const float* __restrict__ att_vd,
                                                    float* __restrict__ ao_s,
                                                    float* __restrict__ ao_d,
                                                    int rowoff) {
  __shared__ short smem[2 * 128 * 64];   // sA | sB, reused as C-tile in epilogue
  __shared__ float vsh[ATT == 1 ? 2048 : (ATT == 2 ? 256 : 1)];
  short* sA = smem;
  short* sB = smem + 128 * 64;
  float* Cf = (float*)Cv;
  unsigned short* Cb = (unsigned short*)Cv;

  const int tid = threadIdx.x;
  const int lane = tid & 63, w = tid >> 6;

  const int gx = gridDim.x;
  int wg = blockIdx.y * gx + blockIdx.x;
  if (SWZ) {
    const int nwg = gx * gridDim.y;
    int orig = wg;
    int q = nwg >> 3, r = nwg & 7;
    int xcd = orig & 7, idx = orig >> 3;
    wg = (xcd < r ? xcd * (q + 1) : r * (q + 1) + (xcd - r) * q) + idx;
  }
  const int m0 = (wg / gx) * 128, n0 = (wg % gx) * 128;

  // stage attention v-slices for the fused epilogue dots (any later barrier
  // orders these writes before the epilogue reads)
  if (ATT == 1) {
    for (int i = tid; i < 1024; i += 512) {
      int h = i >> 7, c = i & 127;
      vsh[i] = att_vs[h * 256 + n0 + c];
      vsh[1024 + i] = att_vd[h * 256 + n0 + c];
    }
  } else if (ATT == 2) {
    if (tid < 128) {
      vsh[tid] = att_vs[n0 + tid];
      vsh[128 + tid] = att_vd[n0 + tid];
    }
  }

  const int koff = BDIAG ? (n0 >> 8) << 8 : 0;
  const int wm = (w & 3) * 32, wn = (w >> 2) * 64;
  const int fr = lane & 15;
  const int frs = fr & 7;
  const int quad = lane >> 4;

  f32x4 acc[2][4];
#pragma unroll
  for (int i = 0; i < 2; ++i)
#pragma unroll
    for (int j = 0; j < 4; ++j) acc[i][j] = (f32x4){0.f, 0.f, 0.f, 0.f};

  for (int k0 = 0; k0 < K; k0 += 64) {
#pragma unroll
    for (int i = 0; i < 2; ++i) {
      int c = i * 512 + tid;
      int row = c >> 3, kc = c & 7;
      int kcs = kc ^ (row & 7);            // XOR swizzle (global side)
      int grow = m0 + row;
      if (grow >= M) grow = M - 1;
      async_copy16(A + (size_t)grow * lda + koff + k0 + kcs * 8, &sA[(i * 512 + w * 64) * 8]);
    }
#pragma unroll
    for (int i = 0; i < 2; ++i) {
      int c = i * 512 + tid;
      int row = c >> 3, kc = c & 7;
      int kcs = kc ^ (row & 7);
      async_copy16(W + (size_t)(n0 + row) * K + k0 + kcs * 8, &sB[(i * 512 + w * 64) * 8]);
    }
    __syncthreads();

#pragma unroll
    for (int ks = 0; ks < 2; ++ks) {
      bf16x8 af[2], bfr[4];
#pragma unroll
      for (int mi = 0; mi < 2; ++mi) {
        int row = wm + mi * 16 + fr;
        af[mi] = *(const bf16x8*)&sA[(row * 8 + ((ks * 4 + quad) ^ frs)) * 8];
      }
#pragma unroll
      for (int ni = 0; ni < 4; ++ni) {
        int row = wn + ni * 16 + fr;
        bfr[ni] = *(const bf16x8*)&sB[(row * 8 + ((ks * 4 + quad) ^ frs)) * 8];
      }
#pragma unroll
      for (int mi = 0; mi < 2; ++mi)
#pragma unroll
        for (int ni = 0; ni < 4; ++ni)
          acc[mi][ni] = __builtin_amdgcn_mfma_f32_16x16x32_bf16(
              af[mi], bfr[ni], acc[mi][ni], 0, 0, 0);
    }
    __syncthreads();
  }

  if (C_BF16) {
    unsigned short* hsh = (unsigned short*)smem;    // 128*128 u16 = 32 KB
#pragma unroll
    for (int mi = 0; mi < 2; ++mi)
#pragma unroll
      for (int ni = 0; ni < 4; ++ni) {
        int col = wn + ni * 16 + fr;
        float bv = BIAS ? bias[n0 + col] : 0.f;
        f32x4 v = acc[mi][ni];
#pragma unroll
        for (int r = 0; r < 4; ++r) {
          int row = wm + mi * 16 + quad * 4 + r;
          float x = v[r] + bv;
          if (RELU) x = fmaxf(x, 0.f);
          hsh[row * 128 + (col ^ (((row >> 2) & 3) << 5))] = f2bf(x);
        }
      }
    __syncthreads();
#pragma unroll
    for (int i = 0; i < 4; ++i) {
      int slot = i * 512 + tid;          // 0..2047 = 128 rows x 16 col-groups
      int row = slot >> 4, cg = slot & 15;
      int colbase = cg * 8;
      bf16x8 val = *(const bf16x8*)&hsh[row * 128 + (colbase ^ (((row >> 2) & 3) << 5))];
      int grow = m0 + row;
      if (grow < M)
        *(bf16x8*)(Cb + (size_t)grow * Nout + n0 + colbase) = val;
    }

    // fused attention partial dots over this col-block (reads hsh, which is
    // unchanged since the last barrier)
    if (ATT != 0) {
      int row = tid >> 2, q = tid & 3;   // 4 threads/row, 32 cols each
      int grow = m0 + row;
      if (ATT == 1) {
        float s8[8], d8[8];
#pragma unroll
        for (int h = 0; h < 8; ++h) { s8[h] = 0.f; d8[h] = 0.f; }
#pragma unroll
        for (int i = 0; i < 32; ++i) {
          int col = q * 32 + i;
          float hx = bf2f(hsh[row * 128 + (col ^ (((row >> 2) & 3) << 5))]);
#pragma unroll
          for (int h = 0; h < 8; ++h) {
            s8[h] += hx * vsh[h * 128 + col];
            d8[h] += hx * vsh[1024 + h * 128 + col];
          }
        }
#pragma unroll
        for (int h = 0; h < 8; ++h) {
          s8[h] += __shfl_down(s8[h], 2); s8[h] += __shfl_down(s8[h], 1);
          d8[h] += __shfl_down(d8[h], 2); d8[h] += __shfl_down(d8[h], 1);
        }
        if (q == 0 && grow < M) {
#pragma unroll
          for (int h = 0; h < 8; ++h) {
            atomicAdd(&ao_s[(size_t)(rowoff + grow) * 8 + h], s8[h]);
            atomicAdd(&ao_d[(size_t)(rowoff + grow) * 8 + h], d8[h]);
          }
        }
      } else {
        float s = 0.f, d = 0.f;
#pragma unroll
        for (int i = 0; i < 32; ++i) {
          int col = q * 32 + i;
          float hx = bf2f(hsh[row * 128 + (col ^ (((row >> 2) & 3) << 5))]);
          s += hx * vsh[col];
          d += hx * vsh[128 + col];
        }
        s += __shfl_down(s, 2); s += __shfl_down(s, 1);
        d += __shfl_down(d, 2); d += __shfl_down(d, 1);
        if (q == 0 && grow < M) {
          atomicAdd(&ao_s[rowoff + grow], s);
          atomicAdd(&ao_d[rowoff + grow], d);
        }
      }
    }
  } else {
#pragma unroll
    for (int mi = 0; mi < 2; ++mi)
#pragma unroll
      for (int ni = 0; ni < 4; ++ni) {
        int col = n0 + wn + ni * 16 + fr;
        float bv = BIAS ? bias[col] : 0.f;
        f32x4 v = acc[mi][ni];
#pragma unroll
        for (int r = 0; r < 4; ++r) {
          int row = m0 + wm + mi * 16 + quad * 4 + r;
          if (row < M) {
            float x = v[r] + bv;
            if (RELU) x = fmaxf(x, 0.f);
            Cf[(size_t)row * Nout + col] = x;
          }
        }
      }
  }
}

// ---------------------------------------------------------------------------
// Edge materialization + degree counts (fused). int64/int32 auto-detect.
__global__ void build_count(const void* __restrict__ edges_raw, int E, int N,
                            int* __restrict__ esrc, int* __restrict__ edst,
                            int* __restrict__ cnt1, int* __restrict__ cnt2, int E1) {
  const long long* p64 = (const long long*)edges_raw;
  const int* p32 = (const int*)edges_raw;
  bool is64 = true;
#pragma unroll
  for (int i = 0; i < 8; ++i) {
    long long v = p64[i];
    if (v < 0 || v >= N) is64 = false;
  }
  int idx = blockIdx.x * 256 + threadIdx.x;
  if (idx >= E1) return;
  int s, d;
  if (idx < E) {
    if (is64) { s = (int)p64[idx]; d = (int)p64[E + idx]; }
    else      { s = p32[idx];      d = p32[E + idx]; }
  } else {
    s = d = idx - E;
  }
  esrc[idx] = s;
  edst[idx] = d;
  atomicAdd(&cnt1[d], 1);
  atomicAdd(&cnt2[s], 1);
}

// ---------------------------------------------------------------------------
// Shuffle-based single-block scan: 3 barriers per 1024-chunk.
__device__ __forceinline__ void scan_one(const int* __restrict__ cnt,
                                         int* __restrict__ indptr,
                                         int* __restrict__ cur, int N, int* buf) {
  int t = threadIdx.x, lane = t & 63, w = t >> 6;
  int running = 0;
  for (int base = 0; base < N; base += 1024) {
    int v = (base + t < N) ? cnt[base + t] : 0;
    int incl = v;
#pragma unroll
    for (int off = 1; off < 64; off <<= 1) {
      int y = __shfl_up(incl, off);
      if (lane >= off) incl += y;
    }
    if (lane == 63) buf[w] = incl;
    __syncthreads();
    if (t < 16) {
      int x = buf[t];
#pragma unroll
      for (int off = 1; off < 16; off <<= 1) {
        int y = __shfl_up(x, off);
        if (t >= off) x += y;
      }
      buf[t] = x;
    }
    __syncthreads();
    int woff = w ? buf[w - 1] : 0;
    int tot = buf[15];
    if (base + t < N) {
      int excl = running + woff + incl - v;
      indptr[base + t] = excl;
      cur[base + t] = excl;
    }
    running += tot;
    __syncthreads();
  }
  if (t == 0) indptr[N] = running;
  __syncthreads();
}

// Two blocks: block 0 scans direction 1, block 1 scans direction 2.
__global__ __launch_bounds__(1024) void scan2_kernel(const int* cnt1, int* indptr1, int* cur1,
                                                     const int* cnt2, int* indptr2, int* cur2,
                                                     int N) {
  __shared__ int buf[16];
  if (blockIdx.x == 0) scan_one(cnt1, indptr1, cur1, N, buf);
  else                 scan_one(cnt2, indptr2, cur2, N, buf);
}

// scatter neighbor node-ids directly.
__global__ void scatter_edges(const int* __restrict__ esrc, const int* __restrict__ edst,
                              int* __restrict__ cur1, int* __restrict__ cur2,
                              int* __restrict__ nbr1, int* __restrict__ nbr2, int E1) {
  int e = blockIdx.x * 256 + threadIdx.x;
  if (e >= E1) return;
  int s = esrc[e], d = edst[e];
  int p1 = atomicAdd(&cur1[d], 1);
  nbr1[p1] = s;
  int p2 = atomicAdd(&cur2[s], 1);
  nbr2[p2] = d;
}

// ---------------------------------------------------------------------------
// conv1 aggregation with FUSED softmax (8 heads), wave-per-dst (4/block).
// NO-MAX deferred-normalization softmax (r23): p = exp(e) directly,
// unnormalized p in LDS for the broadcast j-loop, per-lane partial psum;
// ONE sum-butterfly per head after the loop.
__global__ __launch_bounds__(256) void agg1_fused(const unsigned short* __restrict__ xb,
                                                  const float* __restrict__ a_s,
                                                  const float* __restrict__ a_d,
                                                  const int* __restrict__ indptr,
                                                  const int* __restrict__ nbr,
                                                  unsigned short* __restrict__ agg,
                                                  int N) {
  __shared__ float al_sh[4][64 * 8];
  const int w = threadIdx.x >> 6, lane = threadIdx.x & 63;
  const int dst = blockIdx.x * 4 + w;
  if (dst >= N) return;
  const int start = indptr[dst];
  const int deg = indptr[dst + 1] - start;
  const int c0 = lane * 4;

  float ad[8];
  *(float4*)&ad[0] = *(const float4*)&a_d[dst * 8];
  *(float4*)&ad[4] = *(const float4*)&a_d[dst * 8 + 4];

  float psum[8];
#pragma unroll
  for (int h = 0; h < 8; ++h) psum[h] = 0.f;

  float acc[8][4];
#pragma unroll
  for (int h = 0; h < 8; ++h)
#pragma unroll
    for (int i = 0; i < 4; ++i) acc[h][i] = 0.f;

  for (int base = 0; base < deg; base += 64) {
    int cnt = min(64, deg - base);
    int s = 0;
    if (lane < cnt) {
      s = nbr[start + base + lane];
      float as[8];
      *(float4*)&as[0] = *(const float4*)&a_s[s * 8];
      *(float4*)&as[4] = *(const float4*)&a_s[s * 8 + 4];
      float p8[8];
#pragma unroll
      for (int h = 0; h < 8; ++h) {
        float e = as[h] + ad[h];
        e = e > 0.f ? e : NEG_SLOPE * e;
        float pv = __expf(e);
        p8[h] = pv;
        psum[h] += pv;
      }
#pragma unroll
      for (int h = 0; h < 8; ++h) al_sh[w][lane * 8 + h] = p8[h];
    }
    __builtin_amdgcn_wave_barrier();
    for (int j = 0; j < cnt; ++j) {
      int sj = __shfl(s, j);
      f32x4 alo = *(const f32x4*)&al_sh[w][j * 8];
      f32x4 ahi = *(const f32x4*)&al_sh[w][j * 8 + 4];
      ushort4 xv = *(const ushort4*)(xb + (size_t)sj * 256 + c0);
      float x0 = bf2f(xv.x), x1 = bf2f(xv.y), x2 = bf2f(xv.z), x3 = bf2f(xv.w);
#pragma unroll
      for (int h = 0; h < 4; ++h) {
        acc[h][0] += alo[h] * x0; acc[h][1] += alo[h] * x1;
        acc[h][2] += alo[h] * x2; acc[h][3] += alo[h] * x3;
      }
#pragma unroll
      for (int h = 0; h < 4; ++h) {
        acc[h + 4][0] += ahi[h] * x0; acc[h + 4][1] += ahi[h] * x1;
        acc[h + 4][2] += ahi[h] * x2; acc[h + 4][3] += ahi[h] * x3;
      }
    }
    __builtin_amdgcn_wave_barrier();
  }

  // single deferred sum-reduce per head
  float inv[8];
#pragma unroll
  for (int h = 0; h < 8; ++h) {
    float t = psum[h];
#pragma unroll
    for (int off = 32; off; off >>= 1) t += __shfl_xor(t, off);
    inv[h] = 1.f / (t + 1e-16f);
  }

  unsigned short* op = agg + (size_t)dst * 2048;
#pragma unroll
  for (int h = 0; h < 8; ++h) {
    unsigned short ov[4];
#pragma unroll
    for (int i = 0; i < 4; ++i) ov[i] = f2bf(acc[h][i] * inv[h]);
    *((ushort4*)(op + h * 256 + c0)) = *((const ushort4*)ov);
  }
}

// ---------------------------------------------------------------------------
// conv2 aggregation with FUSED softmax (1 head), wave-per-dst, dst in [Nc,N).
// No-max deferred-normalization (r23); LDS-free.
__global__ __launch_bounds__(256) void agg2_fused(const unsigned short* __restrict__ h2,
                                                  const float* __restrict__ a_s,
                                                  const float* __restrict__ a_d,
                                                  const int* __restrict__ indptr,
                                                  const int* __restrict__ nbr,
                                                  const float* __restrict__ b2,
                                                  unsigned short* __restrict__ x3,
                                                  int Nc, int Ncol) {
  const int w = threadIdx.x >> 6, lane = threadIdx.x & 63;
  const int i0 = blockIdx.x * 4 + w;
  if (i0 >= Ncol) return;
  const int dst = Nc + i0;
  const int start = indptr[dst];
  const int deg = indptr[dst + 1] - start;
  const float ad = a_d[dst];
  float psum = 0.f;
  float acc[4] = {0.f, 0.f, 0.f, 0.f};
  const int c0 = lane * 4;

  for (int base = 0; base < deg; base += 64) {
    int cnt = min(64, deg - base);
    int s = 0;
    float p = 0.f;
    if (lane < cnt) {
      s = nbr[start + base + lane];
      float e = a_s[s] + ad;
      e = e > 0.f ? e : NEG_SLOPE * e;
      p = __expf(e);
      psum += p;
    }
    for (int j = 0; j < cnt; ++j) {
      int sj = __shfl(s, j);
      float al = __shfl(p, j);
      ushort4 hv = *(const ushort4*)(h2 + (size_t)sj * 256 + c0);
      acc[0] += al * bf2f(hv.x);
      acc[1] += al * bf2f(hv.y);
      acc[2] += al * bf2f(hv.z);
      acc[3] += al * bf2f(hv.w);
    }
  }

  float t = psum;
#pragma unroll
  for (int off = 32; off; off >>= 1) t += __shfl_xor(t, off);
  float inv = 1.f / (t + 1e-16f);

  float4 bv = *(const float4*)&b2[c0];
  unsigned short ov[4];
  ov[0] = f2bf(fmaxf(acc[0] * inv + bv.x, 0.f));
  ov[1] = f2bf(fmaxf(acc[1] * inv + bv.y, 0.f));
  ov[2] = f2bf(fmaxf(acc[2] * inv + bv.z, 0.f));
  ov[3] = f2bf(fmaxf(acc[3] * inv + bv.w, 0.f));
  *((ushort4*)(x3 + (size_t)i0 * 256 + c0)) = *((const ushort4*)ov);
}

// ---------------------------------------------------------------------------
extern "C" void kernel_launch(void* const* d_in, const int* in_sizes, int n_in,
                              void* d_out, int out_size, void* d_ws, size_t ws_size,
                              hipStream_t stream) {
  (void)n_in; (void)out_size; (void)ws_size;
  const float* constraints = (const float*)d_in[0];
  const float* columns     = (const float*)d_in[1];
  const void*  edges       = d_in[2];
  const float* W_node = (const float*)d_in[3];
  const float* b_node = (const float*)d_in[4];
  const float* W_col  = (const float*)d_in[5];
  const float* b_col  = (const float*)d_in[6];
  const float* W1       = (const float*)d_in[7];
  const float* att_src1 = (const float*)d_in[8];
  const float* att_dst1 = (const float*)d_in[9];
  const float* b1       = (const float*)d_in[10];
  const float* W2       = (const float*)d_in[11];
  const float* att_src2 = (const float*)d_in[12];
  const float* att_dst2 = (const float*)d_in[13];
  const float* b2       = (const float*)d_in[14];
  const float* W_out    = (const float*)d_in[15];
  const float* b_out    = (const float*)d_in[16];

  const int Nc   = in_sizes[0] / 64;
  const int Ncol = in_sizes[1] / 128;
  const int E    = in_sizes[2] / 2;
  const int N    = Nc + Ncol;
  const int E1   = E + N;

  char* p = (char*)d_ws;
  size_t off = 0;
  auto alloc = [&](size_t nbytes) -> void* {
    void* r = p + off;
    off = (off + nbytes + 255) & ~(size_t)255;
    return r;
  };
  unsigned short* Wn_b  = (unsigned short*)alloc(2ull * 256 * 64);
  unsigned short* Wc_b  = (unsigned short*)alloc(2ull * 256 * 128);
  unsigned short* W1b   = (unsigned short*)alloc(2ull * 2048 * 256);
  unsigned short* W2b   = (unsigned short*)alloc(2ull * 256 * 2048);
  unsigned short* Woutb = (unsigned short*)alloc(2ull * 128 * 256);
  unsigned short* consb = (unsigned short*)alloc(2ull * (size_t)Nc * 64);
  unsigned short* colsb = (unsigned short*)alloc(2ull * (size_t)Ncol * 128);
  unsigned short* xb    = (unsigned short*)alloc(2ull * (size_t)N * 256);
  float* v_s1 = (float*)alloc(sizeof(float) * 8 * 256);
  float* v_d1 = (float*)alloc(sizeof(float) * 8 * 256);

  // zero-initialized region: cnt1/cnt2 + attention-dot accumulators
  size_t zoff0 = off;
  int* cnt1 = (int*)alloc(4ull * 2 * N);
  int* cnt2 = cnt1 + N;
  float* a_s1 = (float*)alloc(sizeof(float) * (size_t)N * 8);
  float* a_d1 = (float*)alloc(sizeof(float) * (size_t)N * 8);
  float* a_s2 = (float*)alloc(sizeof(float) * (size_t)N);
  float* a_d2 = (float*)alloc(sizeof(float) * (size_t)N);
  size_t zbytes = off - zoff0;

  int* indptr1 = (int*)alloc(4ull * (N + 1));
  int* cur1    = (int*)alloc(4ull * N);
  int* indptr2 = (int*)alloc(4ull * (N + 1));
  int* cur2    = (int*)alloc(4ull * N);
  int* esrc = (int*)alloc(4ull * E1);
  int* edst = (int*)alloc(4ull * E1);
  int* nbr1 = (int*)alloc(4ull * E1);
  int* nbr2 = (int*)alloc(4ull * E1);
  unsigned short* agg = (unsigned short*)alloc(2ull * (size_t)N * 2048);
  unsigned short* x2  = (unsigned short*)alloc(2ull * (size_t)N * 2048);
  unsigned short* h2b = (unsigned short*)alloc(2ull * (size_t)N * 256);
  unsigned short* x3 = (unsigned short*)alloc(2ull * (size_t)Ncol * 256);

  hipMemsetAsync(cnt1, 0, zbytes, stream);
  prep<<<1024, 256, 0, stream>>>(W_node, W_col, W1, W2, W_out, constraints, columns,
                                 att_src1, att_dst1,
                                 Wn_b, Wc_b, W1b, W2b, Woutb, consb, colsb,
                                 v_s1, v_d1, Nc * 64, Ncol * 128);

  // encoder (MFMA, bf16 -> xb) with FUSED conv1 attention dots (ATT=1)
  gemm_mfma_bt<true, true, true, false, false, 1><<<dim3(2, (Nc + 127) / 128), 512, 0, stream>>>(
      consb, Wn_b, b_node, xb, Nc, 64, 256, 64, v_s1, v_d1, a_s1, a_d1, 0);
  gemm_mfma_bt<true, true, true, false, false, 1><<<dim3(2, (Ncol + 127) / 128), 512, 0, stream>>>(
      colsb, Wc_b, b_col, xb + (size_t)Nc * 256, Ncol, 128, 256, 128, v_s1, v_d1, a_s1, a_d1, Nc);

  // graph CSR (both directions, neighbor ids stored directly)
  build_count<<<(E1 + 255) / 256, 256, 0, stream>>>(edges, E, N, esrc, edst, cnt1, cnt2, E1);
  scan2_kernel<<<2, 1024, 0, stream>>>(cnt1, indptr1, cur1, cnt2, indptr2, cur2, N);
  scatter_edges<<<(E1 + 255) / 256, 256, 0, stream>>>(esrc, edst, cur1, cur2, nbr1, nbr2, E1);

  // conv1: fused no-max-softmax aggregation, then block-diag projection
  // (swizzled: measured -4us, FETCH 81->52MB)
  agg1_fused<<<(N + 3) / 4, 256, 0, stream>>>(xb, a_s1, a_d1, indptr1, nbr1, agg, N);
  gemm_mfma_bt<true, true, true, true, true, 0><<<dim3(16, (N + 127) / 128), 512, 0, stream>>>(
      agg, W1b, b1, x2, N, 256, 2048, 2048, nullptr, nullptr, nullptr, nullptr, 0);

  // conv2 projection with FUSED conv2 attention dots (ATT=2; natural order:
  // preserves x2 producer->consumer L2 locality), then fused aggregation
  gemm_mfma_bt<true, false, false, false, false, 2><<<dim3(2, (N + 127) / 128), 512, 0, stream>>>(
      x2, W2b, nullptr, h2b, N, 2048, 256, 2048, att_src2, att_dst2, a_s2, a_d2, 0);
  agg2_fused<<<(Ncol + 3) / 4, 256, 0, stream>>>(h2b, a_s2, a_d2, indptr2, nbr2, b2, x3,
                                                 Nc, Ncol);

  // output projection -> d_out f32
  gemm_mfma_bt<false, true, false, false, false, 0><<<dim3(1, (Ncol + 127) / 128), 512, 0, stream>>>(
      x3, Woutb, b_out, (float*)d_out, Ncol, 256, 128, 256, nullptr, nullptr, nullptr, nullptr, 0);
}

// Round 14
// 332.938 us; speedup vs baseline: 1.0303x; 1.0303x over previous
//
#include <hip/hip_runtime.h>

// ---------------------------------------------------------------------------
// GAT 2-layer forward on MI355X. Round 27 (= round 23, the proven best):
//  - Rounds 25/26: the ATT-fused-epilogue variant hit "MI355X container
//    failed twice" TWICE on the same source. Audit found no defect, but two
//    consecutive failures on one kernel make a third retry low-EV, and its
//    predecessor (r24 LDS-read variant) was a measured regression (339->343,
//    2.57M bank conflicts). Reverting to bank the proven 339.0us.
//  - This source = round 23 verbatim: no-max deferred-normalization softmax
//    in both agg kernels (-22.9us vs r21), selective XCD swizzle (BDIAG
//    conv1-proj only), 2-block scan, fused alpha1, standalone a1/a2_dots.
//  - Session law (5 confirmations): ILP or fusion bought at the cost of
//    blocks/CU or per-barrier staging depth always loses on this workload;
//    block-level TLP is the latency hider.
// ---------------------------------------------------------------------------

#define NEG_SLOPE 0.2f

typedef __attribute__((ext_vector_type(8))) short bf16x8;
typedef __attribute__((ext_vector_type(4))) float f32x4;

__device__ __forceinline__ float bf2f(unsigned short u) {
  return __uint_as_float(((unsigned)u) << 16);
}
__device__ __forceinline__ unsigned short f2bf(float f) {
  unsigned u = __float_as_uint(f);
  u += 0x7fffu + ((u >> 16) & 1u);   // round-to-nearest-even
  return (unsigned short)(u >> 16);
}

__device__ __forceinline__ void async_copy16(const void* g, void* l) {
  __builtin_amdgcn_global_load_lds(
      (const __attribute__((address_space(1))) unsigned int*)g,
      (__attribute__((address_space(3))) unsigned int*)l, 16, 0, 0);
}

// ---------------------------------------------------------------------------
// prep: fold W_node/W_col halves, convert MFMA operands to bf16, and compute
// v_s1/v_d1 = att1 @ W1 (per-head 256-dots) as an extra index range.
__global__ void prep(const float* __restrict__ Wn, const float* __restrict__ Wc,
                     const float* __restrict__ W1, const float* __restrict__ W2,
                     const float* __restrict__ Wout,
                     const float* __restrict__ cons, const float* __restrict__ cols,
                     const float* __restrict__ att_s1, const float* __restrict__ att_d1,
                     unsigned short* __restrict__ Wn_b, unsigned short* __restrict__ Wc_b,
                     unsigned short* __restrict__ W1b, unsigned short* __restrict__ W2b,
                     unsigned short* __restrict__ Woutb,
                     unsigned short* __restrict__ consb, unsigned short* __restrict__ colsb,
                     float* __restrict__ v_s1, float* __restrict__ v_d1,
                     int n_cons, int n_cols) {
  const int S0 = 256 * 64;
  const int S1 = 256 * 128;
  const int S2 = 2048 * 256;
  const int S3 = 256 * 2048;
  const int S4 = 128 * 256;
  const int S5 = 2048;                 // v1 (h,k) items
  int total = S0 + S1 + S2 + S3 + S4 + n_cons + n_cols + S5;
  for (int idx = blockIdx.x * 256 + threadIdx.x; idx < total; idx += gridDim.x * 256) {
    int i = idx;
    if (i < S0) { int o = i >> 6, j = i & 63;
      Wn_b[i] = f2bf(Wn[o * 128 + j] + Wn[o * 128 + 64 + j]); continue; }
    i -= S0;
    if (i < S1) { int o = i >> 7, j = i & 127;
      Wc_b[i] = f2bf(Wc[o * 256 + j] + Wc[o * 256 + 128 + j]); continue; }
    i -= S1;
    if (i < S2) { W1b[i] = f2bf(W1[i]); continue; }
    i -= S2;
    if (i < S3) { W2b[i] = f2bf(W2[i]); continue; }
    i -= S3;
    if (i < S4) { Woutb[i] = f2bf(Wout[i]); continue; }
    i -= S4;
    if (i < n_cons) { consb[i] = f2bf(cons[i]); continue; }
    i -= n_cons;
    if (i < n_cols) { colsb[i] = f2bf(cols[i]); continue; }
    i -= n_cols;
    { // v1: i in [0,2048), h = i>>8, k = i&255
      int h = i >> 8, k = i & 255;
      const float* Wrow = W1 + (size_t)h * 256 * 256 + k;
      const float* as = att_s1 + h * 256;
      const float* ad = att_d1 + h * 256;
      float s = 0.f, d = 0.f;
      for (int c = 0; c < 256; ++c) {
        float w = Wrow[(size_t)c * 256];
        s += as[c] * w;
        d += ad[c] * w;
      }
      v_s1[i] = s; v_d1[i] = d;
    }
  }
}

// ---------------------------------------------------------------------------
// a_s1[n,h] = xb[n,:] . v_s[h,:]  (thread per node; v in LDS, broadcast reads)
__global__ __launch_bounds__(256) void a1_dots(const unsigned short* __restrict__ xb,
                                               const float* __restrict__ v_s,
                                               const float* __restrict__ v_d,
                                               float* __restrict__ a_s,
                                               float* __restrict__ a_d, int N) {
  __shared__ float vs[2048], vd[2048];
  for (int i = threadIdx.x; i < 2048; i += 256) { vs[i] = v_s[i]; vd[i] = v_d[i]; }
  __syncthreads();
  int n = blockIdx.x * 256 + threadIdx.x;
  if (n >= N) return;
  const unsigned short* row = xb + (size_t)n * 256;
  float s[8] = {}, d[8] = {};
  for (int c = 0; c < 256; c += 8) {
    bf16x8 xv = *(const bf16x8*)(row + c);
    float xf[8];
#pragma unroll
    for (int i = 0; i < 8; ++i) xf[i] = bf2f(((const unsigned short*)&xv)[i]);
#pragma unroll
    for (int h = 0; h < 8; ++h)
#pragma unroll
      for (int i = 0; i < 8; ++i) {
        s[h] += xf[i] * vs[h * 256 + c + i];
        d[h] += xf[i] * vd[h * 256 + c + i];
      }
  }
#pragma unroll
  for (int h = 0; h < 8; ++h) { a_s[n * 8 + h] = s[h]; a_d[n * 8 + h] = d[h]; }
}

// ---------------------------------------------------------------------------
// a_s2[n] = h2[n,:] . att_s  (thread per node, 1 head; att vectors in LDS,
// uniform-index broadcast reads -> zero bank conflicts)
__global__ __launch_bounds__(256) void a2_dots(const unsigned short* __restrict__ h2,
                                               const float* __restrict__ att_s,
                                               const float* __restrict__ att_d,
                                               float* __restrict__ a_s,
                                               float* __restrict__ a_d, int N) {
  __shared__ float ss[256], sd[256];
  if (threadIdx.x < 256) {
    ss[threadIdx.x] = att_s[threadIdx.x];
    sd[threadIdx.x] = att_d[threadIdx.x];
  }
  __syncthreads();
  int n = blockIdx.x * 256 + threadIdx.x;
  if (n >= N) return;
  const unsigned short* row = h2 + (size_t)n * 256;
  float s = 0.f, d = 0.f;
  for (int c = 0; c < 256; c += 8) {
    bf16x8 xv = *(const bf16x8*)(row + c);
#pragma unroll
    for (int i = 0; i < 8; ++i) {
      float hv = bf2f(((const unsigned short*)&xv)[i]);
      s += hv * ss[c + i];
      d += hv * sd[c + i];
    }
  }
  a_s[n] = s;
  a_d[n] = d;
}

// ---------------------------------------------------------------------------
// bf16 MFMA GEMM, B^T layout: C[m,n] = sum_k A[m, koff+k] * W[n,k] (+bias,relu).
// 512 threads, 8 waves; wave w owns rows [(w&3)*32,+32) x cols [(w>>2)*64,+64)
// of the 128x128 tile. XOR-swizzled staging, coalesced bf16 epilogue via LDS.
// SWZ: XCD-chunked bijective block swizzle (m204) — measured win on the
// BDIAG conv1-proj only; natural dispatch order elsewhere.
template <bool C_BF16, bool BIAS, bool RELU, bool BDIAG, bool SWZ>
__global__ __launch_bounds__(512) void gemm_mfma_bt(const unsigned short* __restrict__ A,
                                                    const unsigned short* __restrict__ W,
                                                    const float* __restrict__ bias,
                                                    void* __restrict__ Cv,
                                                    int M, int K, int Nout, int lda) {
  __shared__ short smem[2 * 128 * 64];   // sA | sB, reused as C-tile in epilogue
  short* sA = smem;
  short* sB = smem + 128 * 64;
  float* Cf = (float*)Cv;
  unsigned short* Cb = (unsigned short*)Cv;

  const int tid = threadIdx.x;
  const int lane = tid & 63, w = tid >> 6;

  const int gx = gridDim.x;
  int wg = blockIdx.y * gx + blockIdx.x;
  if (SWZ) {
    const int nwg = gx * gridDim.y;
    int orig = wg;
    int q = nwg >> 3, r = nwg & 7;
    int xcd = orig & 7, idx = orig >> 3;
    wg = (xcd < r ? xcd * (q + 1) : r * (q + 1) + (xcd - r) * q) + idx;
  }
  const int m0 = (wg / gx) * 128, n0 = (wg % gx) * 128;

  const int koff = BDIAG ? (n0 >> 8) << 8 : 0;
  const int wm = (w & 3) * 32, wn = (w >> 2) * 64;
  const int fr = lane & 15;
  const int frs = fr & 7;
  const int quad = lane >> 4;

  f32x4 acc[2][4];
#pragma unroll
  for (int i = 0; i < 2; ++i)
#pragma unroll
    for (int j = 0; j < 4; ++j) acc[i][j] = (f32x4){0.f, 0.f, 0.f, 0.f};

  for (int k0 = 0; k0 < K; k0 += 64) {
#pragma unroll
    for (int i = 0; i < 2; ++i) {
      int c = i * 512 + tid;
      int row = c >> 3, kc = c & 7;
      int kcs = kc ^ (row & 7);            // XOR swizzle (global side)
      int grow = m0 + row;
      if (grow >= M) grow = M - 1;
      async_copy16(A + (size_t)grow * lda + koff + k0 + kcs * 8, &sA[(i * 512 + w * 64) * 8]);
    }
#pragma unroll
    for (int i = 0; i < 2; ++i) {
      int c = i * 512 + tid;
      int row = c >> 3, kc = c & 7;
      int kcs = kc ^ (row & 7);
      async_copy16(W + (size_t)(n0 + row) * K + k0 + kcs * 8, &sB[(i * 512 + w * 64) * 8]);
    }
    __syncthreads();

#pragma unroll
    for (int ks = 0; ks < 2; ++ks) {
      bf16x8 af[2], bfr[4];
#pragma unroll
      for (int mi = 0; mi < 2; ++mi) {
        int row = wm + mi * 16 + fr;
        af[mi] = *(const bf16x8*)&sA[(row * 8 + ((ks * 4 + quad) ^ frs)) * 8];
      }
#pragma unroll
      for (int ni = 0; ni < 4; ++ni) {
        int row = wn + ni * 16 + fr;
        bfr[ni] = *(const bf16x8*)&sB[(row * 8 + ((ks * 4 + quad) ^ frs)) * 8];
      }
#pragma unroll
      for (int mi = 0; mi < 2; ++mi)
#pragma unroll
        for (int ni = 0; ni < 4; ++ni)
          acc[mi][ni] = __builtin_amdgcn_mfma_f32_16x16x32_bf16(
              af[mi], bfr[ni], acc[mi][ni], 0, 0, 0);
    }
    __syncthreads();
  }

  if (C_BF16) {
    unsigned short* hsh = (unsigned short*)smem;    // 128*128 u16 = 32 KB
#pragma unroll
    for (int mi = 0; mi < 2; ++mi)
#pragma unroll
      for (int ni = 0; ni < 4; ++ni) {
        int col = wn + ni * 16 + fr;
        float bv = BIAS ? bias[n0 + col] : 0.f;
        f32x4 v = acc[mi][ni];
#pragma unroll
        for (int r = 0; r < 4; ++r) {
          int row = wm + mi * 16 + quad * 4 + r;
          float x = v[r] + bv;
          if (RELU) x = fmaxf(x, 0.f);
          hsh[row * 128 + (col ^ (((row >> 2) & 3) << 5))] = f2bf(x);
        }
      }
    __syncthreads();
#pragma unroll
    for (int i = 0; i < 4; ++i) {
      int slot = i * 512 + tid;          // 0..2047 = 128 rows x 16 col-groups
      int row = slot >> 4, cg = slot & 15;
      int colbase = cg * 8;
      bf16x8 val = *(const bf16x8*)&hsh[row * 128 + (colbase ^ (((row >> 2) & 3) << 5))];
      int grow = m0 + row;
      if (grow < M)
        *(bf16x8*)(Cb + (size_t)grow * Nout + n0 + colbase) = val;
    }
  } else {
#pragma unroll
    for (int mi = 0; mi < 2; ++mi)
#pragma unroll
      for (int ni = 0; ni < 4; ++ni) {
        int col = n0 + wn + ni * 16 + fr;
        float bv = BIAS ? bias[col] : 0.f;
        f32x4 v = acc[mi][ni];
#pragma unroll
        for (int r = 0; r < 4; ++r) {
          int row = m0 + wm + mi * 16 + quad * 4 + r;
          if (row < M) {
            float x = v[r] + bv;
            if (RELU) x = fmaxf(x, 0.f);
            Cf[(size_t)row * Nout + col] = x;
          }
        }
      }
  }
}

// ---------------------------------------------------------------------------
// Edge materialization + degree counts (fused). int64/int32 auto-detect.
__global__ void build_count(const void* __restrict__ edges_raw, int E, int N,
                            int* __restrict__ esrc, int* __restrict__ edst,
                            int* __restrict__ cnt1, int* __restrict__ cnt2, int E1) {
  const long long* p64 = (const long long*)edges_raw;
  const int* p32 = (const int*)edges_raw;
  bool is64 = true;
#pragma unroll
  for (int i = 0; i < 8; ++i) {
    long long v = p64[i];
    if (v < 0 || v >= N) is64 = false;
  }
  int idx = blockIdx.x * 256 + threadIdx.x;
  if (idx >= E1) return;
  int s, d;
  if (idx < E) {
    if (is64) { s = (int)p64[idx]; d = (int)p64[E + idx]; }
    else      { s = p32[idx];      d = p32[E + idx]; }
  } else {
    s = d = idx - E;
  }
  esrc[idx] = s;
  edst[idx] = d;
  atomicAdd(&cnt1[d], 1);
  atomicAdd(&cnt2[s], 1);
}

// ---------------------------------------------------------------------------
// Shuffle-based single-block scan: 3 barriers per 1024-chunk.
__device__ __forceinline__ void scan_one(const int* __restrict__ cnt,
                                         int* __restrict__ indptr,
                                         int* __restrict__ cur, int N, int* buf) {
  int t = threadIdx.x, lane = t & 63, w = t >> 6;
  int running = 0;
  for (int base = 0; base < N; base += 1024) {
    int v = (base + t < N) ? cnt[base + t] : 0;
    int incl = v;
#pragma unroll
    for (int off = 1; off < 64; off <<= 1) {
      int y = __shfl_up(incl, off);
      if (lane >= off) incl += y;
    }
    if (lane == 63) buf[w] = incl;
    __syncthreads();
    if (t < 16) {
      int x = buf[t];
#pragma unroll
      for (int off = 1; off < 16; off <<= 1) {
        int y = __shfl_up(x, off);
        if (t >= off) x += y;
      }
      buf[t] = x;
    }
    __syncthreads();
    int woff = w ? buf[w - 1] : 0;
    int tot = buf[15];
    if (base + t < N) {
      int excl = running + woff + incl - v;
      indptr[base + t] = excl;
      cur[base + t] = excl;
    }
    running += tot;
    __syncthreads();
  }
  if (t == 0) indptr[N] = running;
  __syncthreads();
}

// Two blocks: block 0 scans direction 1, block 1 scans direction 2.
__global__ __launch_bounds__(1024) void scan2_kernel(const int* cnt1, int* indptr1, int* cur1,
                                                     const int* cnt2, int* indptr2, int* cur2,
                                                     int N) {
  __shared__ int buf[16];
  if (blockIdx.x == 0) scan_one(cnt1, indptr1, cur1, N, buf);
  else                 scan_one(cnt2, indptr2, cur2, N, buf);
}

// scatter neighbor node-ids directly.
__global__ void scatter_edges(const int* __restrict__ esrc, const int* __restrict__ edst,
                              int* __restrict__ cur1, int* __restrict__ cur2,
                              int* __restrict__ nbr1, int* __restrict__ nbr2, int E1) {
  int e = blockIdx.x * 256 + threadIdx.x;
  if (e >= E1) return;
  int s = esrc[e], d = edst[e];
  int p1 = atomicAdd(&cur1[d], 1);
  nbr1[p1] = s;
  int p2 = atomicAdd(&cur2[s], 1);
  nbr2[p2] = d;
}

// ---------------------------------------------------------------------------
// conv1 aggregation with FUSED softmax (8 heads), wave-per-dst (4/block).
// NO-MAX deferred-normalization softmax: p = exp(e) directly (logits O(1);
// f32 exp safe), unnormalized p in LDS for the broadcast j-loop, per-lane
// partial psum across chunks; ONE sum-butterfly per head AFTER the loop.
__global__ __launch_bounds__(256) void agg1_fused(const unsigned short* __restrict__ xb,
                                                  const float* __restrict__ a_s,
                                                  const float* __restrict__ a_d,
                                                  const int* __restrict__ indptr,
                                                  const int* __restrict__ nbr,
                                                  unsigned short* __restrict__ agg,
                                                  int N) {
  __shared__ float al_sh[4][64 * 8];
  const int w = threadIdx.x >> 6, lane = threadIdx.x & 63;
  const int dst = blockIdx.x * 4 + w;
  if (dst >= N) return;
  const int start = indptr[dst];
  const int deg = indptr[dst + 1] - start;
  const int c0 = lane * 4;

  float ad[8];
  *(float4*)&ad[0] = *(const float4*)&a_d[dst * 8];
  *(float4*)&ad[4] = *(const float4*)&a_d[dst * 8 + 4];

  float psum[8];
#pragma unroll
  for (int h = 0; h < 8; ++h) psum[h] = 0.f;

  float acc[8][4];
#pragma unroll
  for (int h = 0; h < 8; ++h)
#pragma unroll
    for (int i = 0; i < 4; ++i) acc[h][i] = 0.f;

  for (int base = 0; base < deg; base += 64) {
    int cnt = min(64, deg - base);
    int s = 0;
    if (lane < cnt) {
      s = nbr[start + base + lane];
      float as[8];
      *(float4*)&as[0] = *(const float4*)&a_s[s * 8];
      *(float4*)&as[4] = *(const float4*)&a_s[s * 8 + 4];
      float p8[8];
#pragma unroll
      for (int h = 0; h < 8; ++h) {
        float e = as[h] + ad[h];
        e = e > 0.f ? e : NEG_SLOPE * e;
        float pv = __expf(e);
        p8[h] = pv;
        psum[h] += pv;
      }
#pragma unroll
      for (int h = 0; h < 8; ++h) al_sh[w][lane * 8 + h] = p8[h];
    }
    __builtin_amdgcn_wave_barrier();
    for (int j = 0; j < cnt; ++j) {
      int sj = __shfl(s, j);
      f32x4 alo = *(const f32x4*)&al_sh[w][j * 8];
      f32x4 ahi = *(const f32x4*)&al_sh[w][j * 8 + 4];
      ushort4 xv = *(const ushort4*)(xb + (size_t)sj * 256 + c0);
      float x0 = bf2f(xv.x), x1 = bf2f(xv.y), x2 = bf2f(xv.z), x3 = bf2f(xv.w);
#pragma unroll
      for (int h = 0; h < 4; ++h) {
        acc[h][0] += alo[h] * x0; acc[h][1] += alo[h] * x1;
        acc[h][2] += alo[h] * x2; acc[h][3] += alo[h] * x3;
      }
#pragma unroll
      for (int h = 0; h < 4; ++h) {
        acc[h + 4][0] += ahi[h] * x0; acc[h + 4][1] += ahi[h] * x1;
        acc[h + 4][2] += ahi[h] * x2; acc[h + 4][3] += ahi[h] * x3;
      }
    }
    __builtin_amdgcn_wave_barrier();
  }

  // single deferred sum-reduce per head
  float inv[8];
#pragma unroll
  for (int h = 0; h < 8; ++h) {
    float t = psum[h];
#pragma unroll
    for (int off = 32; off; off >>= 1) t += __shfl_xor(t, off);
    inv[h] = 1.f / (t + 1e-16f);
  }

  unsigned short* op = agg + (size_t)dst * 2048;
#pragma unroll
  for (int h = 0; h < 8; ++h) {
    unsigned short ov[4];
#pragma unroll
    for (int i = 0; i < 4; ++i) ov[i] = f2bf(acc[h][i] * inv[h]);
    *((ushort4*)(op + h * 256 + c0)) = *((const ushort4*)ov);
  }
}

// ---------------------------------------------------------------------------
// conv2 aggregation with FUSED softmax (1 head), wave-per-dst, dst in [Nc,N).
// No-max deferred-normalization; LDS-free.
__global__ __launch_bounds__(256) void agg2_fused(const unsigned short* __restrict__ h2,
                                                  const float* __restrict__ a_s,
                                                  const float* __restrict__ a_d,
                                                  const int* __restrict__ indptr,
                                                  const int* __restrict__ nbr,
                                                  const float* __restrict__ b2,
                                                  unsigned short* __restrict__ x3,
                                                  int Nc, int Ncol) {
  const int w = threadIdx.x >> 6, lane = threadIdx.x & 63;
  const int i0 = blockIdx.x * 4 + w;
  if (i0 >= Ncol) return;
  const int dst = Nc + i0;
  const int start = indptr[dst];
  const int deg = indptr[dst + 1] - start;
  const float ad = a_d[dst];
  float psum = 0.f;
  float acc[4] = {0.f, 0.f, 0.f, 0.f};
  const int c0 = lane * 4;

  for (int base = 0; base < deg; base += 64) {
    int cnt = min(64, deg - base);
    int s = 0;
    float p = 0.f;
    if (lane < cnt) {
      s = nbr[start + base + lane];
      float e = a_s[s] + ad;
      e = e > 0.f ? e : NEG_SLOPE * e;
      p = __expf(e);
      psum += p;
    }
    for (int j = 0; j < cnt; ++j) {
      int sj = __shfl(s, j);
      float al = __shfl(p, j);
      ushort4 hv = *(const ushort4*)(h2 + (size_t)sj * 256 + c0);
      acc[0] += al * bf2f(hv.x);
      acc[1] += al * bf2f(hv.y);
      acc[2] += al * bf2f(hv.z);
      acc[3] += al * bf2f(hv.w);
    }
  }

  float t = psum;
#pragma unroll
  for (int off = 32; off; off >>= 1) t += __shfl_xor(t, off);
  float inv = 1.f / (t + 1e-16f);

  float4 bv = *(const float4*)&b2[c0];
  unsigned short ov[4];
  ov[0] = f2bf(fmaxf(acc[0] * inv + bv.x, 0.f));
  ov[1] = f2bf(fmaxf(acc[1] * inv + bv.y, 0.f));
  ov[2] = f2bf(fmaxf(acc[2] * inv + bv.z, 0.f));
  ov[3] = f2bf(fmaxf(acc[3] * inv + bv.w, 0.f));
  *((ushort4*)(x3 + (size_t)i0 * 256 + c0)) = *((const ushort4*)ov);
}

// ---------------------------------------------------------------------------
extern "C" void kernel_launch(void* const* d_in, const int* in_sizes, int n_in,
                              void* d_out, int out_size, void* d_ws, size_t ws_size,
                              hipStream_t stream) {
  (void)n_in; (void)out_size; (void)ws_size;
  const float* constraints = (const float*)d_in[0];
  const float* columns     = (const float*)d_in[1];
  const void*  edges       = d_in[2];
  const float* W_node = (const float*)d_in[3];
  const float* b_node = (const float*)d_in[4];
  const float* W_col  = (const float*)d_in[5];
  const float* b_col  = (const float*)d_in[6];
  const float* W1       = (const float*)d_in[7];
  const float* att_src1 = (const float*)d_in[8];
  const float* att_dst1 = (const float*)d_in[9];
  const float* b1       = (const float*)d_in[10];
  const float* W2       = (const float*)d_in[11];
  const float* att_src2 = (const float*)d_in[12];
  const float* att_dst2 = (const float*)d_in[13];
  const float* b2       = (const float*)d_in[14];
  const float* W_out    = (const float*)d_in[15];
  const float* b_out    = (const float*)d_in[16];

  const int Nc   = in_sizes[0] / 64;
  const int Ncol = in_sizes[1] / 128;
  const int E    = in_sizes[2] / 2;
  const int N    = Nc + Ncol;
  const int E1   = E + N;

  char* p = (char*)d_ws;
  size_t off = 0;
  auto alloc = [&](size_t nbytes) -> void* {
    void* r = p + off;
    off = (off + nbytes + 255) & ~(size_t)255;
    return r;
  };
  unsigned short* Wn_b  = (unsigned short*)alloc(2ull * 256 * 64);
  unsigned short* Wc_b  = (unsigned short*)alloc(2ull * 256 * 128);
  unsigned short* W1b   = (unsigned short*)alloc(2ull * 2048 * 256);
  unsigned short* W2b   = (unsigned short*)alloc(2ull * 256 * 2048);
  unsigned short* Woutb = (unsigned short*)alloc(2ull * 128 * 256);
  unsigned short* consb = (unsigned short*)alloc(2ull * (size_t)Nc * 64);
  unsigned short* colsb = (unsigned short*)alloc(2ull * (size_t)Ncol * 128);
  unsigned short* xb    = (unsigned short*)alloc(2ull * (size_t)N * 256);
  float* v_s1 = (float*)alloc(sizeof(float) * 8 * 256);
  float* v_d1 = (float*)alloc(sizeof(float) * 8 * 256);
  float* a_s1 = (float*)alloc(sizeof(float) * (size_t)N * 8);
  float* a_d1 = (float*)alloc(sizeof(float) * (size_t)N * 8);
  int* esrc = (int*)alloc(4ull * E1);
  int* edst = (int*)alloc(4ull * E1);
  int* cnt1 = (int*)alloc(4ull * 2 * N);
  int* cnt2 = cnt1 + N;
  int* indptr1 = (int*)alloc(4ull * (N + 1));
  int* cur1    = (int*)alloc(4ull * N);
  int* indptr2 = (int*)alloc(4ull * (N + 1));
  int* cur2    = (int*)alloc(4ull * N);
  int* nbr1 = (int*)alloc(4ull * E1);
  int* nbr2 = (int*)alloc(4ull * E1);
  unsigned short* agg = (unsigned short*)alloc(2ull * (size_t)N * 2048);
  unsigned short* x2  = (unsigned short*)alloc(2ull * (size_t)N * 2048);
  unsigned short* h2b = (unsigned short*)alloc(2ull * (size_t)N * 256);
  float* a_s2 = (float*)alloc(sizeof(float) * (size_t)N);
  float* a_d2 = (float*)alloc(sizeof(float) * (size_t)N);
  unsigned short* x3 = (unsigned short*)alloc(2ull * (size_t)Ncol * 256);

  hipMemsetAsync(cnt1, 0, 4ull * 2 * N, stream);
  prep<<<1024, 256, 0, stream>>>(W_node, W_col, W1, W2, W_out, constraints, columns,
                                 att_src1, att_dst1,
                                 Wn_b, Wc_b, W1b, W2b, Woutb, consb, colsb,
                                 v_s1, v_d1, Nc * 64, Ncol * 128);

  // encoder (MFMA, bf16 -> xb)
  gemm_mfma_bt<true, true, true, false, false><<<dim3(2, (Nc + 127) / 128), 512, 0, stream>>>(
      consb, Wn_b, b_node, xb, Nc, 64, 256, 64);
  gemm_mfma_bt<true, true, true, false, false><<<dim3(2, (Ncol + 127) / 128), 512, 0, stream>>>(
      colsb, Wc_b, b_col, xb + (size_t)Nc * 256, Ncol, 128, 256, 128);

  // attention logits for conv1
  a1_dots<<<(N + 255) / 256, 256, 0, stream>>>(xb, v_s1, v_d1, a_s1, a_d1, N);

  // graph CSR (both directions, neighbor ids stored directly)
  build_count<<<(E1 + 255) / 256, 256, 0, stream>>>(edges, E, N, esrc, edst, cnt1, cnt2, E1);
  scan2_kernel<<<2, 1024, 0, stream>>>(cnt1, indptr1, cur1, cnt2, indptr2, cur2, N);
  scatter_edges<<<(E1 + 255) / 256, 256, 0, stream>>>(esrc, edst, cur1, cur2, nbr1, nbr2, E1);

  // conv1: fused no-max-softmax aggregation, then block-diag projection
  // (swizzled: measured -4us, FETCH 81->52MB)
  agg1_fused<<<(N + 3) / 4, 256, 0, stream>>>(xb, a_s1, a_d1, indptr1, nbr1, agg, N);
  gemm_mfma_bt<true, true, true, true, true><<<dim3(16, (N + 127) / 128), 512, 0, stream>>>(
      agg, W1b, b1, x2, N, 256, 2048, 2048);

  // conv2 projection: 128x128-tile MFMA GEMM (natural order: preserves
  // x2 producer->consumer L2 locality), then attention-dot pass, then
  // fused no-max-softmax aggregation over column nodes
  gemm_mfma_bt<true, false, false, false, false><<<dim3(2, (N + 127) / 128), 512, 0, stream>>>(
      x2, W2b, nullptr, h2b, N, 2048, 256, 2048);
  a2_dots<<<(N + 255) / 256, 256, 0, stream>>>(h2b, att_src2, att_dst2, a_s2, a_d2, N);
  agg2_fused<<<(Ncol + 3) / 4, 256, 0, stream>>>(h2b, a_s2, a_d2, indptr2, nbr2, b2, x3,
                                                 Nc, Ncol);

  // output projection -> d_out f32
  gemm_mfma_bt<false, true, false, false, false><<<dim3(1, (Ncol + 127) / 128), 512, 0, stream>>>(
      x3, Woutb, b_out, (float*)d_out, Ncol, 256, 128, 256);
}